// Round 1
// baseline (1369.591 us; speedup 1.0000x reference)
//
#include <hip/hip_runtime.h>
#include <math.h>

#define BS 2048
#define HH 64
#define WW 64
#define SHIFT 2
#define NTH 5

__launch_bounds__(256, 4)
__global__ void wrsl_kernel(const float* __restrict__ fm1,
                            const float* __restrict__ fm2,
                            float* __restrict__ out) {
    __shared__ float lds1[4096];
    __shared__ float lds2[4096];
    __shared__ float red[8];

    const int tid = threadIdx.x;
    const int b = blockIdx.x;
    const float* src1 = fm1 + (size_t)b * 4096;
    const float* src2 = fm2 + (size_t)b * 4096;

    // stage both 64x64 images into LDS (float4, coalesced)
    {
        const float4* s1 = (const float4*)src1;
        const float4* s2 = (const float4*)src2;
        float4* l1 = (float4*)lds1;
        float4* l2 = (float4*)lds2;
        #pragma unroll
        for (int i = 0; i < 4; i++) {
            l1[tid + 256 * i] = s1[tid + 256 * i];
            l2[tid + 256 * i] = s2[tid + 256 * i];
        }
    }
    __syncthreads();

    // rotation constants per theta: t = -(theta_deg) * pi/180, theta_deg = ti-2
    float alp[NTH], bet[NTH];
    #pragma unroll
    for (int ti = 0; ti < NTH; ti++) {
        float t = -(float)(ti - 2) * 0.017453292519943295f;
        alp[ti] = cosf(t);
        bet[ti] = sinf(t);
    }

    const int x = tid & 63;    // this lane's output column
    const int wid = tid >> 6;  // wave id 0..3 (row stripe)
    float best = 3.4028234663852886e38f;

    for (int s = 0; s < 25; s++) {
        const int bh = (s / 5) - SHIFT;
        const int bv = (s % 5) - SHIFT;
        const int ox1 = bh >= 0 ? 0 : -bh;   // r1 col offset into fm1
        const int ox2 = bh >= 0 ? bh : 0;    // r2 col offset into fm2
        const int ow = WW - (bh >= 0 ? bh : -bh);
        const int oy1 = bv >= 0 ? 0 : -bv;
        const int oy2 = bv >= 0 ? bv : 0;
        const int oh = HH - (bv >= 0 ? bv : -bv);
        const float cx = 0.5f * (float)ow;
        const float cy = 0.5f * (float)oh;

        #pragma unroll
        for (int ti = 0; ti < NTH; ti++) {
            const float alpha = alp[ti], beta = bet[ti];
            const float c1 = (1.0f - alpha) * cx - beta * cy;
            const float c2 = beta * cx + (1.0f - alpha) * cy;

            float acc_se = 0.0f, acc_mk = 0.0f;
            if (x < ow) {
                const float xs = (float)x;
                const float hx = fmaf(alpha, xs, c1);   // x-dependent, loop-invariant
                const float hy = fmaf(-beta, xs, c2);
                const float* r1col = lds1 + (oy1 * 64) + (x + ox1);
                for (int y = wid; y < oh; y += 4) {
                    const float ys = (float)y;
                    float xsrc = fmaf(beta, ys, hx);
                    float ysrc = fmaf(alpha, ys, hy);
                    float x0f = floorf(xsrc), y0f = floorf(ysrc);
                    float wx = xsrc - x0f, wyf = ysrc - y0f;
                    int x0 = (int)x0f, y0 = (int)y0f;
                    // separable validity folded into 1D weights
                    float ax0 = (x0 >= 0 && x0 < ow)          ? (1.0f - wx)  : 0.0f;
                    float ax1 = (x0 >= -1 && x0 < ow - 1)     ? wx           : 0.0f;
                    float ay0 = (y0 >= 0 && y0 < oh)          ? (1.0f - wyf) : 0.0f;
                    float ay1 = (y0 >= -1 && y0 < oh - 1)     ? wyf          : 0.0f;
                    int xc0 = min(max(x0, 0), ow - 1);
                    int xc1 = min(max(x0 + 1, 0), ow - 1);
                    int yc0 = min(max(y0, 0), oh - 1);
                    int yc1 = min(max(y0 + 1, 0), oh - 1);
                    const float* row0 = lds2 + (yc0 + oy2) * 64 + ox2;
                    const float* row1 = lds2 + (yc1 + oy2) * 64 + ox2;
                    float t00 = row0[xc0], t01 = row0[xc1];
                    float t10 = row1[xc0], t11 = row1[xc1];
                    float rr2 = ay0 * fmaf(ax0, t00, ax1 * t01)
                              + ay1 * fmaf(ax0, t10, ax1 * t11);
                    float mk = (ay0 + ay1) * (ax0 + ax1);
                    float r1v = r1col[y * 64];
                    float d = r1v - rr2;
                    acc_se = fmaf(d * d, mk, acc_se);
                    acc_mk += mk;
                }
            }
            // wave reduce (64 lanes)
            #pragma unroll
            for (int off = 32; off; off >>= 1) {
                acc_se += __shfl_xor(acc_se, off);
                acc_mk += __shfl_xor(acc_mk, off);
            }
            if ((tid & 63) == 0) { red[2 * wid] = acc_se; red[2 * wid + 1] = acc_mk; }
            __syncthreads();
            float se  = red[0] + red[2] + red[4] + red[6];
            float mks = red[1] + red[3] + red[5] + red[7];
            best = fminf(best, se / mks);
            __syncthreads();
        }
    }
    if (tid == 0) out[b] = best;
}

extern "C" void kernel_launch(void* const* d_in, const int* in_sizes, int n_in,
                              void* d_out, int out_size, void* d_ws, size_t ws_size,
                              hipStream_t stream) {
    const float* fm1 = (const float*)d_in[0];
    const float* fm2 = (const float*)d_in[1];
    float* out = (float*)d_out;
    wrsl_kernel<<<BS, 256, 0, stream>>>(fm1, fm2, out);
}

// Round 2
// 868.315 us; speedup vs baseline: 1.5773x; 1.5773x over previous
//
#include <hip/hip_runtime.h>
#include <math.h>

#define NB 4      // batches per block
#define NTH 5     // thetas
#define GUARD 96  // LDS guard dwords on each side (covers idx in [-65, +65] overrun)

__launch_bounds__(512, 4)
__global__ void wrsl_kernel(const float* __restrict__ fm1,
                            const float* __restrict__ fm2,
                            float* __restrict__ out) {
    __shared__ float lds_raw[GUARD + NB * 4096 + GUARD];
    __shared__ float red[8][26];
    __shared__ float dists[NB * NTH];

    float* img2 = lds_raw + GUARD;

    const int tid = threadIdx.x;
    const int blk = blockIdx.x;
    const size_t base_elt = (size_t)blk * NB * 4096;

    // stage fm2: 4 consecutive batch images = one contiguous 64KB region
    {
        const float4* src = (const float4*)(fm2 + base_elt);
        float4* dst = (float4*)img2;
        #pragma unroll
        for (int i = 0; i < 8; i++)
            dst[tid + 512 * i] = src[tid + 512 * i];
    }
    if (tid < GUARD) {             // zero guards so OOB-of-window taps are finite
        lds_raw[tid] = 0.0f;
        lds_raw[GUARD + NB * 4096 + tid] = 0.0f;
    }

    // per-theta rotation constants
    float alp[NTH], bet[NTH];
    #pragma unroll
    for (int ti = 0; ti < NTH; ti++) {
        float t = -(float)(ti - 2) * 0.017453292519943295f;
        alp[ti] = cosf(t);
        bet[ti] = sinf(t);
    }

    const int lane = tid & 63;  // output column
    const int wid = tid >> 6;   // wave id 0..7 = row stripe
    const float xs = (float)lane;

    __syncthreads();

    float best = 3.4028234663852886e38f;

    for (int s = 0; s < 25; s++) {
        const int bh = (s / 5) - 2;
        const int bv = (s % 5) - 2;
        const int ox1 = bh >= 0 ? 0 : -bh;
        const int ox2 = bh >= 0 ? bh : 0;
        const int ow = 64 - (bh >= 0 ? bh : -bh);
        const int oy1 = bv >= 0 ? 0 : -bv;
        const int oy2 = bv >= 0 ? bv : 0;
        const int oh = 64 - (bv >= 0 ? bv : -bv);
        const float cx = 0.5f * (float)ow;
        const float cy = 0.5f * (float)oh;
        const bool xin = lane < ow;

        // r1 column values -> registers (reused across 5 thetas); L2-resident
        float r1v[NB][8];
        #pragma unroll
        for (int k = 0; k < 8; k++) {
            const int y = wid + 8 * k;
            const bool v = xin && (y < oh);
            #pragma unroll
            for (int b = 0; b < NB; b++)
                r1v[b][k] = v ? fm1[base_elt + b * 4096 + (size_t)((oy1 + y) * 64 + ox1 + lane)]
                              : 0.0f;
        }

        float acc_se[NTH][NB];
        float acc_mk[NTH];
        #pragma unroll
        for (int ti = 0; ti < NTH; ti++) {
            acc_mk[ti] = 0.0f;
            #pragma unroll
            for (int b = 0; b < NB; b++) acc_se[ti][b] = 0.0f;
        }

        #pragma unroll
        for (int ti = 0; ti < NTH; ti++) {
            const float alpha = alp[ti], beta = bet[ti];
            const float c1 = (1.0f - alpha) * cx - beta * cy;
            const float c2 = beta * cx + (1.0f - alpha) * cy;
            const float hx = fmaf(alpha, xs, c1);  // per-lane, y-invariant
            const float hy = fmaf(-beta, xs, c2);
            #pragma unroll
            for (int k = 0; k < 8; k++) {
                const int y = wid + 8 * k;
                if (y < oh) {  // wave-uniform branch
                    const float yf = (float)y;
                    const float xsrc = fmaf(beta, yf, hx);
                    const float ysrc = fmaf(alpha, yf, hy);
                    const float x0f = floorf(xsrc), y0f = floorf(ysrc);
                    const float wx = xsrc - x0f, wy = ysrc - y0f;
                    const int x0 = (int)x0f, y0 = (int)y0f;
                    // zero-weight predicates (batch-independent)
                    const float ax0 = (xin && (unsigned)x0 < (unsigned)ow) ? (1.0f - wx) : 0.0f;
                    const float ax1 = (xin && (unsigned)(x0 + 1) < (unsigned)ow) ? wx : 0.0f;
                    const float ay0 = ((unsigned)y0 < (unsigned)oh) ? (1.0f - wy) : 0.0f;
                    const float ay1 = ((unsigned)(y0 + 1) < (unsigned)oh) ? wy : 0.0f;
                    // clamp for addressing only (weights already zeroed)
                    const int x0c = min(max(x0, -1), ow - 1);
                    const int y0c = min(max(y0, -1), oh - 1);
                    const float mk = (ax0 + ax1) * (ay0 + ay1);
                    acc_mk[ti] += mk;
                    const int idx = (y0c + oy2) * 64 + (x0c + ox2);
                    #pragma unroll
                    for (int b = 0; b < NB; b++) {
                        const float* p = img2 + b * 4096 + idx;
                        const float t00 = p[0], t01 = p[1];
                        const float t10 = p[64], t11 = p[65];
                        const float h0 = fmaf(ax1, t01, ax0 * t00);
                        const float h1 = fmaf(ax1, t11, ax0 * t10);
                        const float rr2 = fmaf(ay0, h0, ay1 * h1);
                        const float d = r1v[b][k] - rr2;
                        acc_se[ti][b] = fmaf(d * d, mk, acc_se[ti][b]);
                    }
                }
            }
        }

        // wave-level reduce of 25 values
        #pragma unroll
        for (int ti = 0; ti < NTH; ti++) {
            #pragma unroll
            for (int off = 32; off; off >>= 1)
                acc_mk[ti] += __shfl_xor(acc_mk[ti], off);
            #pragma unroll
            for (int b = 0; b < NB; b++) {
                #pragma unroll
                for (int off = 32; off; off >>= 1)
                    acc_se[ti][b] += __shfl_xor(acc_se[ti][b], off);
            }
        }
        if (lane == 0) {
            #pragma unroll
            for (int ti = 0; ti < NTH; ti++) {
                red[wid][ti] = acc_mk[ti];  // cols 0..4: mk per theta
                #pragma unroll
                for (int b = 0; b < NB; b++)
                    red[wid][5 + b * NTH + ti] = acc_se[ti][b];
            }
        }
        __syncthreads();
        if (tid < NB * NTH) {
            const int ti = tid % NTH;
            float se = 0.0f, mks = 0.0f;
            #pragma unroll
            for (int w = 0; w < 8; w++) {
                se += red[w][5 + tid];
                mks += red[w][ti];
            }
            dists[tid] = se / mks;
        }
        __syncthreads();
        if (tid < NB) {
            #pragma unroll
            for (int ti = 0; ti < NTH; ti++)
                best = fminf(best, dists[tid * NTH + ti]);
        }
    }
    if (tid < NB) out[blk * NB + tid] = best;
}

extern "C" void kernel_launch(void* const* d_in, const int* in_sizes, int n_in,
                              void* d_out, int out_size, void* d_ws, size_t ws_size,
                              hipStream_t stream) {
    const float* fm1 = (const float*)d_in[0];
    const float* fm2 = (const float*)d_in[1];
    float* out = (float*)d_out;
    wrsl_kernel<<<2048 / NB, 512, 0, stream>>>(fm1, fm2, out);
}

// Round 3
// 713.796 us; speedup vs baseline: 1.9187x; 1.2165x over previous
//
#include <hip/hip_runtime.h>
#include <math.h>

#define NB 2      // batches per block (interleaved in LDS as float2)
#define NTH 5
#define GF2 80    // guard float2s each side (covers tap index in [-65, +65+row])

__launch_bounds__(512, 4)
__global__ void wrsl_kernel(const float* __restrict__ fm1,
                            const float* __restrict__ fm2,
                            float* __restrict__ out) {
    __shared__ __align__(16) float2 raw1[GF2 + 4096 + GF2];
    __shared__ __align__(16) float2 raw2[GF2 + 4096 + GF2];
    __shared__ float red[8][15];
    __shared__ float dists[10];

    float2* img1 = raw1 + GF2;
    float2* img2 = raw2 + GF2;

    const int tid = threadIdx.x;
    const int blk = blockIdx.x;
    const size_t base = (size_t)blk * (NB * 4096);

    // stage both images, batch-interleaved: img[p] = {batch0[p], batch1[p]}
    {
        const float4* a0 = (const float4*)(fm1 + base);
        const float4* a1 = (const float4*)(fm1 + base + 4096);
        const float4* b0 = (const float4*)(fm2 + base);
        const float4* b1 = (const float4*)(fm2 + base + 4096);
        #pragma unroll
        for (int i = 0; i < 2; i++) {
            const int p = tid + 512 * i;   // float4-granule index (1024 total)
            float4 xa = a0[p], xb = a1[p];
            ((float4*)(img1 + p * 4))[0] = make_float4(xa.x, xb.x, xa.y, xb.y);
            ((float4*)(img1 + p * 4))[1] = make_float4(xa.z, xb.z, xa.w, xb.w);
            float4 ya = b0[p], yb = b1[p];
            ((float4*)(img2 + p * 4))[0] = make_float4(ya.x, yb.x, ya.y, yb.y);
            ((float4*)(img2 + p * 4))[1] = make_float4(ya.z, yb.z, ya.w, yb.w);
        }
        if (tid < GF2) {  // zero guards: OOB-of-window taps must be finite
            raw1[tid] = make_float2(0.f, 0.f);
            raw1[GF2 + 4096 + tid] = make_float2(0.f, 0.f);
            raw2[tid] = make_float2(0.f, 0.f);
            raw2[GF2 + 4096 + tid] = make_float2(0.f, 0.f);
        }
    }

    const int lane = tid & 63;  // output column
    const int wid = tid >> 6;   // wave 0..7 = row stripe
    const float xs = (float)lane;

    __syncthreads();

    float best = 3.4028234663852886e38f;

    for (int s = 0; s < 25; s++) {
        const int bh = (s / 5) - 2;
        const int bv = (s % 5) - 2;
        const int ox1 = bh >= 0 ? 0 : -bh;
        const int ox2 = bh >= 0 ? bh : 0;
        const int ow = 64 - (bh >= 0 ? bh : -bh);
        const int oy1 = bv >= 0 ? 0 : -bv;
        const int oy2 = bv >= 0 ? bv : 0;
        const int oh = 64 - (bv >= 0 ? bv : -bv);
        const float cx = 0.5f * (float)ow;
        const float cy = 0.5f * (float)oh;
        const bool xin = lane < ow;

        // r1 column (both batches) -> 16 regs, reused across 5 thetas
        float2 r1v[8];
        #pragma unroll
        for (int k = 0; k < 8; k++) {
            const int y = wid + 8 * k;
            r1v[k] = (y < oh) ? img1[(oy1 + y) * 64 + (ox1 + lane)]
                              : make_float2(0.f, 0.f);
        }

        for (int ti = 0; ti < NTH; ti++) {
            const float t = (float)(2 - ti) * 0.017453292519943295f;
            const float alpha = cosf(t);
            const float beta = sinf(t);
            const float hx = fmaf(alpha, xs, (1.0f - alpha) * cx - beta * cy);
            const float hy = fmaf(-beta, xs, beta * cx + (1.0f - alpha) * cy);
            float as0 = 0.f, as1 = 0.f, am = 0.f;
            #pragma unroll
            for (int k = 0; k < 8; k++) {
                const int y = wid + 8 * k;
                if (y < oh) {  // wave-uniform
                    const float yf = (float)y;
                    const float xsrc = fmaf(beta, yf, hx);
                    const float ysrc = fmaf(alpha, yf, hy);
                    const float x0f = floorf(xsrc), y0f = floorf(ysrc);
                    const float wx = xsrc - x0f, wy = ysrc - y0f;
                    const int x0 = (int)x0f, y0 = (int)y0f;
                    const float ax0 = (xin && (unsigned)x0 < (unsigned)ow) ? (1.f - wx) : 0.f;
                    const float ax1 = (xin && (unsigned)(x0 + 1) < (unsigned)ow) ? wx : 0.f;
                    const float ay0 = ((unsigned)y0 < (unsigned)oh) ? (1.f - wy) : 0.f;
                    const float ay1 = ((unsigned)(y0 + 1) < (unsigned)oh) ? wy : 0.f;
                    const int x0c = min(max(x0, -1), ow - 1);   // addressing only
                    const int y0c = min(max(y0, -1), oh - 1);
                    const float mk = (ax0 + ax1) * (ay0 + ay1);
                    const float2* p = img2 + (y0c + oy2) * 64 + (x0c + ox2);
                    const float2 t00 = p[0], t01 = p[1];
                    const float2 t10 = p[64], t11 = p[65];
                    const float h0x = fmaf(ax1, t01.x, ax0 * t00.x);
                    const float h0y = fmaf(ax1, t01.y, ax0 * t00.y);
                    const float h1x = fmaf(ax1, t11.x, ax0 * t10.x);
                    const float h1y = fmaf(ax1, t11.y, ax0 * t10.y);
                    const float r0 = fmaf(ay0, h0x, ay1 * h1x);
                    const float r1 = fmaf(ay0, h0y, ay1 * h1y);
                    const float d0 = r1v[k].x - r0;
                    const float d1 = r1v[k].y - r1;
                    as0 = fmaf(d0 * d0, mk, as0);
                    as1 = fmaf(d1 * d1, mk, as1);
                    am += mk;
                }
            }
            #pragma unroll
            for (int off = 32; off; off >>= 1) {
                as0 += __shfl_xor(as0, off);
                as1 += __shfl_xor(as1, off);
                am  += __shfl_xor(am, off);
            }
            if (lane == 0) {
                red[wid][ti] = am;           // cols 0..4: mk per theta
                red[wid][5 + ti] = as0;      // cols 5..9: se batch0
                red[wid][10 + ti] = as1;     // cols 10..14: se batch1
            }
        }
        __syncthreads();
        if (tid < 10) {
            const int ti = tid % 5;
            float se = 0.f, mks = 0.f;
            #pragma unroll
            for (int w = 0; w < 8; w++) { se += red[w][5 + tid]; mks += red[w][ti]; }
            dists[tid] = se / mks;
        }
        __syncthreads();
        if (tid < 2) {
            #pragma unroll
            for (int ti = 0; ti < NTH; ti++)
                best = fminf(best, dists[tid * 5 + ti]);
        }
    }
    if (tid < 2) out[blk * 2 + tid] = best;
}

extern "C" void kernel_launch(void* const* d_in, const int* in_sizes, int n_in,
                              void* d_out, int out_size, void* d_ws, size_t ws_size,
                              hipStream_t stream) {
    const float* fm1 = (const float*)d_in[0];
    const float* fm2 = (const float*)d_in[1];
    float* out = (float*)d_out;
    wrsl_kernel<<<2048 / NB, 512, 0, stream>>>(fm1, fm2, out);
}

// Round 4
// 560.647 us; speedup vs baseline: 2.4429x; 1.2732x over previous
//
#include <hip/hip_runtime.h>
#include <math.h>

#define NB 4
#define NTH 5
#define GF4 68   // guard float4s each side of img2 (tap idx range [-65, 4160])

__launch_bounds__(1024, 4)
__global__ void wrsl_kernel(const float* __restrict__ fm1,
                            const float* __restrict__ fm2,
                            float* __restrict__ out) {
    __shared__ __align__(16) float4 img1[4096];
    __shared__ __align__(16) float4 raw2[GF4 + 4096 + GF4];
    __shared__ float red[16][25];
    __shared__ float colsum[25];

    float4* img2 = raw2 + GF4;
    const int tid = threadIdx.x;
    const int blk = blockIdx.x;
    const size_t base = (size_t)blk * (NB * 4096);

    // stage both images, 4 batches interleaved as float4 per pixel
    {
        const float4* s1 = (const float4*)(fm1 + base);
        const float4* s2 = (const float4*)(fm2 + base);
        float4 a0 = s1[tid], a1 = s1[tid + 1024], a2 = s1[tid + 2048], a3 = s1[tid + 3072];
        img1[4 * tid + 0] = make_float4(a0.x, a1.x, a2.x, a3.x);
        img1[4 * tid + 1] = make_float4(a0.y, a1.y, a2.y, a3.y);
        img1[4 * tid + 2] = make_float4(a0.z, a1.z, a2.z, a3.z);
        img1[4 * tid + 3] = make_float4(a0.w, a1.w, a2.w, a3.w);
        float4 b0 = s2[tid], b1 = s2[tid + 1024], b2 = s2[tid + 2048], b3 = s2[tid + 3072];
        img2[4 * tid + 0] = make_float4(b0.x, b1.x, b2.x, b3.x);
        img2[4 * tid + 1] = make_float4(b0.y, b1.y, b2.y, b3.y);
        img2[4 * tid + 2] = make_float4(b0.z, b1.z, b2.z, b3.z);
        img2[4 * tid + 3] = make_float4(b0.w, b1.w, b2.w, b3.w);
        if (tid < GF4) {  // zero guards: OOB-of-window taps must be FINITE (raw LDS can hold NaN bits)
            raw2[tid] = make_float4(0.f, 0.f, 0.f, 0.f);
            raw2[GF4 + 4096 + tid] = make_float4(0.f, 0.f, 0.f, 0.f);
        }
    }

    const int lane = tid & 63;  // output column
    const int wid = tid >> 6;   // wave 0..15 = row stripe
    const float xs = (float)lane;

    float alp[NTH], bet[NTH];
    #pragma unroll
    for (int ti = 0; ti < NTH; ti++) {
        float t = (float)(2 - ti) * 0.017453292519943295f;
        alp[ti] = cosf(t);
        bet[ti] = sinf(t);
    }

    __syncthreads();

    float best = 3.4028234663852886e38f;  // meaningful on tid<4 only

    for (int s = 0; s < 25; s++) {
        const int bh = (s / 5) - 2;
        const int bv = (s % 5) - 2;
        const int ox1 = bh >= 0 ? 0 : -bh;
        const int ox2 = bh >= 0 ? bh : 0;
        const int ow = 64 - (bh >= 0 ? bh : -bh);
        const int oy1 = bv >= 0 ? 0 : -bv;
        const int oy2 = bv >= 0 ? bv : 0;
        const int oh = 64 - (bv >= 0 ? bv : -bv);
        const float cx = 0.5f * (float)ow;
        const float cy = 0.5f * (float)oh;
        const float xinf = (lane < ow) ? 1.0f : 0.0f;
        const int xcap = ox1 + min(lane, ow - 1);

        // r1 column (4 batches) -> 16 regs, reused across 5 thetas
        float4 r1v[4];
        #pragma unroll
        for (int k = 0; k < 4; k++) {
            const int y = wid + 16 * k;
            r1v[k] = img1[(oy1 + min(y, oh - 1)) * 64 + xcap];
        }
        const float4* img2s = img2 + (oy2 * 64 + ox2);

        #pragma unroll
        for (int ti = 0; ti < NTH; ti++) {
            const float alpha = alp[ti], beta = bet[ti];
            const float hx = fmaf(alpha, xs, (1.0f - alpha) * cx - beta * cy);
            const float hy = fmaf(-beta, xs, beta * cx + (1.0f - alpha) * cy);
            float as0 = 0.f, as1 = 0.f, as2 = 0.f, as3 = 0.f, am = 0.f;
            #pragma unroll
            for (int k = 0; k < 4; k++) {
                const int y = wid + 16 * k;
                if (y < oh) {  // wave-uniform
                    const float yf = (float)y;
                    const float xsrc = fmaf(beta, yf, hx);
                    const float ysrc = fmaf(alpha, yf, hy);
                    const float x0f = floorf(xsrc), y0f = floorf(ysrc);
                    const float wx = xsrc - x0f, wy = ysrc - y0f;
                    const int x0 = (int)x0f, y0 = (int)y0f;
                    const float ax0 = ((unsigned)x0 < (unsigned)ow) ? (1.f - wx) : 0.f;
                    const float ax1 = ((unsigned)(x0 + 1) < (unsigned)ow) ? wx : 0.f;
                    const float ay0 = ((unsigned)y0 < (unsigned)oh) ? (1.f - wy) : 0.f;
                    const float ay1 = ((unsigned)(y0 + 1) < (unsigned)oh) ? wy : 0.f;
                    const int x0c = min(max(x0, -1), ow - 1);   // addressing only
                    const int y0c = min(max(y0, -1), oh - 1);
                    const float mk = (ax0 + ax1) * (ay0 + ay1) * xinf;
                    const float4* p = img2s + (y0c * 64 + x0c);
                    const float4 t00 = p[0], t01 = p[1];
                    const float4 t10 = p[64], t11 = p[65];
                    // batch 0..3 = components x..w
                    float h0 = fmaf(ax1, t01.x, ax0 * t00.x);
                    float h1 = fmaf(ax1, t11.x, ax0 * t10.x);
                    float r  = fmaf(ay0, h0, ay1 * h1);
                    float d  = r1v[k].x - r;
                    as0 = fmaf(d * d, mk, as0);
                    h0 = fmaf(ax1, t01.y, ax0 * t00.y);
                    h1 = fmaf(ax1, t11.y, ax0 * t10.y);
                    r  = fmaf(ay0, h0, ay1 * h1);
                    d  = r1v[k].y - r;
                    as1 = fmaf(d * d, mk, as1);
                    h0 = fmaf(ax1, t01.z, ax0 * t00.z);
                    h1 = fmaf(ax1, t11.z, ax0 * t10.z);
                    r  = fmaf(ay0, h0, ay1 * h1);
                    d  = r1v[k].z - r;
                    as2 = fmaf(d * d, mk, as2);
                    h0 = fmaf(ax1, t01.w, ax0 * t00.w);
                    h1 = fmaf(ax1, t11.w, ax0 * t10.w);
                    r  = fmaf(ay0, h0, ay1 * h1);
                    d  = r1v[k].w - r;
                    as3 = fmaf(d * d, mk, as3);
                    am += mk;
                }
            }
            #pragma unroll
            for (int off = 32; off; off >>= 1) {
                as0 += __shfl_xor(as0, off);
                as1 += __shfl_xor(as1, off);
                as2 += __shfl_xor(as2, off);
                as3 += __shfl_xor(as3, off);
                am  += __shfl_xor(am, off);
            }
            if (lane == 0) {
                red[wid][ti]          = am;   // cols 0..4: mk per theta
                red[wid][5 + 0 * NTH + ti] = as0;
                red[wid][5 + 1 * NTH + ti] = as1;
                red[wid][5 + 2 * NTH + ti] = as2;
                red[wid][5 + 3 * NTH + ti] = as3;
            }
        }
        __syncthreads();               // B1
        if (tid < 25) {
            float v = 0.f;
            #pragma unroll
            for (int w = 0; w < 16; w++) v += red[w][tid];
            colsum[tid] = v;
        }
        __syncthreads();               // B2
        if (tid < NB) {
            #pragma unroll
            for (int ti = 0; ti < NTH; ti++)
                best = fminf(best, colsum[5 + tid * NTH + ti] / colsum[ti]);
        }
    }
    if (tid < NB) out[blk * NB + tid] = best;
}

extern "C" void kernel_launch(void* const* d_in, const int* in_sizes, int n_in,
                              void* d_out, int out_size, void* d_ws, size_t ws_size,
                              hipStream_t stream) {
    const float* fm1 = (const float*)d_in[0];
    const float* fm2 = (const float*)d_in[1];
    float* out = (float*)d_out;
    wrsl_kernel<<<2048 / NB, 1024, 0, stream>>>(fm1, fm2, out);
}

// Round 5
// 452.982 us; speedup vs baseline: 3.0235x; 1.2377x over previous
//
#include <hip/hip_runtime.h>
#include <math.h>

#define NB 8
#define NTH 5
#define GLO 132   // low guard uint4s (min tap idx -130)
#define GHI 264   // high guard uint4s (max tap idx 4355)

__device__ __forceinline__ unsigned pack2(float a, float b) {
    unsigned ua = (__float_as_uint(a) + 0x8000u) >> 16;
    unsigned ub = (__float_as_uint(b) + 0x8000u) & 0xFFFF0000u;
    return ua | ub;
}
__device__ __forceinline__ float lo16(unsigned u) { return __uint_as_float(u << 16); }
__device__ __forceinline__ float hi16(unsigned u) { return __uint_as_float(u & 0xFFFF0000u); }

// sum over 8-lane groups: xor1,xor2 via DPP (VALU pipe), xor4 via ds_swizzle
__device__ __forceinline__ float red8(float x) {
    int t = __builtin_amdgcn_update_dpp(0, __float_as_int(x), 0xB1, 0xF, 0xF, true); // quad_perm [1,0,3,2]
    x += __int_as_float(t);
    t = __builtin_amdgcn_update_dpp(0, __float_as_int(x), 0x4E, 0xF, 0xF, true);     // quad_perm [2,3,0,1]
    x += __int_as_float(t);
    t = __builtin_amdgcn_ds_swizzle(__float_as_int(x), 0x101F);                      // xor 4
    x += __int_as_float(t);
    return x;
}

__launch_bounds__(1024, 4)
__global__ void wrsl_kernel(const float* __restrict__ fm1,
                            const float* __restrict__ fm2,
                            float* __restrict__ out) {
    __shared__ uint4 img1u[4096];
    __shared__ uint4 raw2[GLO + 4096 + GHI];
    __shared__ float redm[16][8][45];
    __shared__ float colsum[45];

    uint4* img2u = raw2 + GLO;
    const int tid = threadIdx.x;
    const int blk = blockIdx.x;
    const size_t base = (size_t)blk * (NB * 4096);

    // stage: 8 batches per pixel packed as bf16 (rounded), both images
    #pragma unroll
    for (int i = 0; i < 4; i++) {
        const int p = tid + 1024 * i;
        uint4 w;
        w.x = pack2(fm1[base + 0 * 4096 + p], fm1[base + 1 * 4096 + p]);
        w.y = pack2(fm1[base + 2 * 4096 + p], fm1[base + 3 * 4096 + p]);
        w.z = pack2(fm1[base + 4 * 4096 + p], fm1[base + 5 * 4096 + p]);
        w.w = pack2(fm1[base + 6 * 4096 + p], fm1[base + 7 * 4096 + p]);
        img1u[p] = w;
        uint4 v;
        v.x = pack2(fm2[base + 0 * 4096 + p], fm2[base + 1 * 4096 + p]);
        v.y = pack2(fm2[base + 2 * 4096 + p], fm2[base + 3 * 4096 + p]);
        v.z = pack2(fm2[base + 4 * 4096 + p], fm2[base + 5 * 4096 + p]);
        v.w = pack2(fm2[base + 6 * 4096 + p], fm2[base + 7 * 4096 + p]);
        img2u[p] = v;
    }
    if (tid < GLO + GHI) {  // zero guards: OOB-of-window taps read finite zeros
        const int g = (tid < GLO) ? tid : (4096 + tid);
        raw2[g] = make_uint4(0u, 0u, 0u, 0u);
    }

    const int lane = tid & 63;  // output column
    const int wid = tid >> 6;   // wave 0..15 = row stripe
    const float xs = (float)lane;

    __syncthreads();

    float best = 3.4028234663852886e38f;  // meaningful on tid<8 only

    constexpr float ALP[5] = {0.99939082701909576f, 0.99984769515639127f, 1.0f,
                              0.99984769515639127f, 0.99939082701909576f};
    constexpr float BET[5] = {0.03489949670250097f, 0.01745240643728351f, 0.0f,
                              -0.01745240643728351f, -0.03489949670250097f};

    for (int s = 0; s < 25; s++) {
        const int bh = (s / 5) - 2;
        const int bv = (s % 5) - 2;
        const int ox1 = bh >= 0 ? 0 : -bh;
        const int ox2 = bh >= 0 ? bh : 0;
        const int ow = 64 - (bh >= 0 ? bh : -bh);
        const int oy1 = bv >= 0 ? 0 : -bv;
        const int oy2 = bv >= 0 ? bv : 0;
        const int oh = 64 - (bv >= 0 ? bv : -bv);
        const float cx = 0.5f * (float)ow;
        const float cy = 0.5f * (float)oh;
        const float xinf = (lane < ow) ? 1.0f : 0.0f;
        const int xcap = ox1 + min(lane, ow - 1);

        // r1 column (8 batches, packed) -> 16 regs, reused across 5 thetas
        uint4 r1p[4];
        #pragma unroll
        for (int k = 0; k < 4; k++)
            r1p[k] = img1u[(oy1 + min(wid + 16 * k, oh - 1)) * 64 + xcap];
        const uint4* img2s = img2u + (oy2 * 64 + ox2);

        #pragma unroll
        for (int ti = 0; ti < NTH; ti++) {
            const float alpha = ALP[ti], beta = BET[ti];
            const float hx = fmaf(alpha, xs, (1.0f - alpha) * cx - beta * cy);
            const float hy = fmaf(-beta, xs, beta * cx + (1.0f - alpha) * cy);
            float as[NB];
            #pragma unroll
            for (int j = 0; j < NB; j++) as[j] = 0.0f;
            float am = 0.0f;
            #pragma unroll
            for (int k = 0; k < 4; k++) {
                const int y = wid + 16 * k;
                if (y < oh) {  // wave-uniform
                    const float yf = (float)y;
                    const float xsrc = fmaf(beta, yf, hx);
                    const float ysrc = fmaf(alpha, yf, hy);
                    const float x0f = floorf(xsrc), y0f = floorf(ysrc);
                    const float wx = xsrc - x0f, wy = ysrc - y0f;
                    const int x0 = (int)x0f, y0 = (int)y0f;
                    const float ax0 = ((unsigned)x0 < (unsigned)ow) ? (1.f - wx) : 0.f;
                    const float ax1 = ((unsigned)(x0 + 1) < (unsigned)ow) ? wx : 0.f;
                    const float ay0 = ((unsigned)y0 < (unsigned)oh) ? (1.f - wy) : 0.f;
                    const float ay1 = ((unsigned)(y0 + 1) < (unsigned)oh) ? wy : 0.f;
                    const float w00 = ay0 * ax0, w01 = ay0 * ax1;
                    const float w10 = ay1 * ax0, w11 = ay1 * ax1;
                    const float mk = (ax0 + ax1) * (ay0 + ay1) * xinf;
                    am += mk;
                    // no clamps: weights are zero OOB, guards keep reads in-bounds
                    const uint4* p = img2s + (y0 * 64 + x0);
                    const uint4 q00 = p[0], q01 = p[1];
                    const uint4 q10 = p[64], q11 = p[65];
                    #define ONE_BATCH(COMP, EXT, VI)                                   \
                    {                                                                  \
                        float r = w00 * EXT(q00.COMP);                                 \
                        r = fmaf(w01, EXT(q01.COMP), r);                               \
                        r = fmaf(w10, EXT(q10.COMP), r);                               \
                        r = fmaf(w11, EXT(q11.COMP), r);                               \
                        const float d = EXT(r1p[k].COMP) - r;                          \
                        as[VI] = fmaf(d * d, mk, as[VI]);                              \
                    }
                    ONE_BATCH(x, lo16, 0) ONE_BATCH(x, hi16, 1)
                    ONE_BATCH(y, lo16, 2) ONE_BATCH(y, hi16, 3)
                    ONE_BATCH(z, lo16, 4) ONE_BATCH(z, hi16, 5)
                    ONE_BATCH(w, lo16, 6) ONE_BATCH(w, hi16, 7)
                    #undef ONE_BATCH
                }
            }
            // group-of-8 reduction (2 DPP + 1 swizzle per value)
            am = red8(am);
            #pragma unroll
            for (int j = 0; j < NB; j++) as[j] = red8(as[j]);
            if ((lane & 7) == 0) {
                float* dst = &redm[wid][lane >> 3][0];
                #pragma unroll
                for (int j = 0; j < NB; j++) dst[j * NTH + ti] = as[j];
                dst[40 + ti] = am;
            }
        }
        __syncthreads();  // B1
        if (tid < 45) {
            float ssum = 0.0f;
            const float* rf = &redm[0][0][0];
            #pragma unroll 16
            for (int j = 0; j < 128; j++) ssum += rf[j * 45 + tid];
            colsum[tid] = ssum;
        }
        __syncthreads();  // B2
        if (tid < NB) {
            #pragma unroll
            for (int ti = 0; ti < NTH; ti++)
                best = fminf(best, colsum[tid * NTH + ti] / colsum[40 + ti]);
        }
    }
    if (tid < NB) out[blk * NB + tid] = best;
}

extern "C" void kernel_launch(void* const* d_in, const int* in_sizes, int n_in,
                              void* d_out, int out_size, void* d_ws, size_t ws_size,
                              hipStream_t stream) {
    const float* fm1 = (const float*)d_in[0];
    const float* fm2 = (const float*)d_in[1];
    float* out = (float*)d_out;
    wrsl_kernel<<<2048 / NB, 1024, 0, stream>>>(fm1, fm2, out);
}

// Round 6
// 309.451 us; speedup vs baseline: 4.4259x; 1.4638x over previous
//
#include <hip/hip_runtime.h>
#include <hip/hip_fp16.h>
#include <math.h>

#define NB 8
#define NTH 5
#define GLO 132   // low guard H8s (min tap idx ~ -67, margin)
#define GHI 264   // high guard H8s (max tap idx ~ 4166, margin)

struct __align__(16) H8 { __half2 h[4]; };  // 8 batches packed fp16 per pixel

// sum over 8-lane groups: xor1,xor2 via DPP (VALU pipe), xor4 via ds_swizzle
__device__ __forceinline__ float red8(float x) {
    int t = __builtin_amdgcn_update_dpp(0, __float_as_int(x), 0xB1, 0xF, 0xF, true); // quad_perm [1,0,3,2]
    x += __int_as_float(t);
    t = __builtin_amdgcn_update_dpp(0, __float_as_int(x), 0x4E, 0xF, 0xF, true);     // quad_perm [2,3,0,1]
    x += __int_as_float(t);
    t = __builtin_amdgcn_ds_swizzle(__float_as_int(x), 0x101F);                      // xor 4
    x += __int_as_float(t);
    return x;
}

__launch_bounds__(1024, 1)   // LDS caps at 1 block/CU anyway; allow full 128 VGPRs
__global__ void wrsl_kernel(const float* __restrict__ fm1,
                            const float* __restrict__ fm2,
                            float* __restrict__ out) {
    __shared__ H8 img1h[4096];
    __shared__ H8 raw2[GLO + 4096 + GHI];
    __shared__ float redm[16][8][45];
    __shared__ float colsum[45];

    H8* img2h = raw2 + GLO;
    const int tid = threadIdx.x;
    const int blk = blockIdx.x;
    const size_t base = (size_t)blk * (NB * 4096);

    // stage: 8 batches per pixel packed as fp16 pairs, both images
    #pragma unroll
    for (int i = 0; i < 4; i++) {
        const int p = tid + 1024 * i;
        H8 w, v;
        #pragma unroll
        for (int j = 0; j < 4; j++) {
            w.h[j] = __floats2half2_rn(fm1[base + (2 * j) * 4096 + p],
                                       fm1[base + (2 * j + 1) * 4096 + p]);
            v.h[j] = __floats2half2_rn(fm2[base + (2 * j) * 4096 + p],
                                       fm2[base + (2 * j + 1) * 4096 + p]);
        }
        img1h[p] = w;
        img2h[p] = v;
    }
    if (tid < GLO + GHI) {  // zero guards: OOB-of-window taps read finite zeros
        const int g = (tid < GLO) ? tid : (4096 + tid);
        *((uint4*)&raw2[g]) = make_uint4(0u, 0u, 0u, 0u);
    }

    const int lane = tid & 63;  // output column
    const int wid = tid >> 6;   // wave 0..15 = row stripe
    const float xs = (float)lane;

    __syncthreads();

    float best = 3.4028234663852886e38f;  // meaningful on tid<8 only

    constexpr float ALP[5] = {0.99939082701909576f, 0.99984769515639127f, 1.0f,
                              0.99984769515639127f, 0.99939082701909576f};
    constexpr float BET[5] = {0.03489949670250097f, 0.01745240643728351f, 0.0f,
                              -0.01745240643728351f, -0.03489949670250097f};

    for (int s = 0; s < 25; s++) {
        const int bh = (s / 5) - 2;
        const int bv = (s % 5) - 2;
        const int ox1 = bh >= 0 ? 0 : -bh;
        const int ox2 = bh >= 0 ? bh : 0;
        const int ow = 64 - (bh >= 0 ? bh : -bh);
        const int oy1 = bv >= 0 ? 0 : -bv;
        const int oy2 = bv >= 0 ? bv : 0;
        const int oh = 64 - (bv >= 0 ? bv : -bv);
        const float cx = 0.5f * (float)ow;
        const float cy = 0.5f * (float)oh;
        const float xinf = (lane < ow) ? 1.0f : 0.0f;
        const int xcap = ox1 + min(lane, ow - 1);

        // r1 column (8 batches packed) -> 16 regs, reused across 5 thetas
        H8 r1p[4];
        #pragma unroll
        for (int k = 0; k < 4; k++)
            r1p[k] = img1h[(oy1 + min(wid + 16 * k, oh - 1)) * 64 + xcap];
        const H8* img2s = img2h + (oy2 * 64 + ox2);

        #pragma unroll
        for (int ti = 0; ti < NTH; ti++) {
            const float alpha = ALP[ti], beta = BET[ti];
            const float hx = fmaf(alpha, xs, (1.0f - alpha) * cx - beta * cy);
            const float hy = fmaf(-beta, xs, beta * cx + (1.0f - alpha) * cy);
            const __half2 z2 = __floats2half2_rn(0.0f, 0.0f);
            __half2 se[4] = {z2, z2, z2, z2};
            float am = 0.0f;
            #pragma unroll
            for (int k = 0; k < 4; k++) {
                const int y = wid + 16 * k;
                if (y < oh) {  // wave-uniform
                    const float yf = (float)y;
                    const float xsrc = fmaf(beta, yf, hx);
                    const float ysrc = fmaf(alpha, yf, hy);
                    const float x0f = floorf(xsrc), y0f = floorf(ysrc);
                    const float wx = xsrc - x0f, wy = ysrc - y0f;
                    const int x0 = (int)x0f, y0 = (int)y0f;
                    const float ax0 = ((unsigned)x0 < (unsigned)ow) ? (1.f - wx) : 0.f;
                    const float ax1 = ((unsigned)(x0 + 1) < (unsigned)ow) ? wx : 0.f;
                    const float ay0 = ((unsigned)y0 < (unsigned)oh) ? (1.f - wy) : 0.f;
                    const float ay1 = ((unsigned)(y0 + 1) < (unsigned)oh) ? wy : 0.f;
                    const float mk = (ax0 + ax1) * (ay0 + ay1) * xinf;
                    am += mk;
                    const __half2 w00p = __float2half2_rn(ay0 * ax0);
                    const __half2 w01p = __float2half2_rn(ay0 * ax1);
                    const __half2 w10p = __float2half2_rn(ay1 * ax0);
                    const __half2 w11p = __float2half2_rn(ay1 * ax1);
                    const __half2 mkp  = __float2half2_rn(mk);
                    // no clamps: weights are zero OOB, guards keep reads in-bounds
                    const H8* p = img2s + (y0 * 64 + x0);
                    const H8 q00 = p[0], q01 = p[1];
                    const H8 q10 = p[64], q11 = p[65];
                    #pragma unroll
                    for (int j = 0; j < 4; j++) {
                        __half2 r = __hmul2(w00p, q00.h[j]);
                        r = __hfma2(w01p, q01.h[j], r);
                        r = __hfma2(w10p, q10.h[j], r);
                        r = __hfma2(w11p, q11.h[j], r);
                        const __half2 d = __hsub2(r1p[k].h[j], r);
                        se[j] = __hfma2(__hmul2(d, d), mkp, se[j]);
                    }
                }
            }
            // unpack to f32 and reduce over 8-lane groups
            float as[NB];
            #pragma unroll
            for (int j = 0; j < 4; j++) {
                const float2 f = __half22float2(se[j]);
                as[2 * j] = f.x;
                as[2 * j + 1] = f.y;
            }
            am = red8(am);
            #pragma unroll
            for (int j = 0; j < NB; j++) as[j] = red8(as[j]);
            if ((lane & 7) == 0) {
                float* dst = &redm[wid][lane >> 3][0];
                #pragma unroll
                for (int j = 0; j < NB; j++) dst[j * NTH + ti] = as[j];
                dst[40 + ti] = am;
            }
        }
        __syncthreads();  // B1
        if (tid < 45) {
            float ssum = 0.0f;
            const float* rf = &redm[0][0][0];
            #pragma unroll 16
            for (int j = 0; j < 128; j++) ssum += rf[j * 45 + tid];
            colsum[tid] = ssum;
        }
        __syncthreads();  // B2
        if (tid < NB) {
            #pragma unroll
            for (int ti = 0; ti < NTH; ti++)
                best = fminf(best, colsum[tid * NTH + ti] / colsum[40 + ti]);
        }
    }
    if (tid < NB) out[blk * NB + tid] = best;
}

extern "C" void kernel_launch(void* const* d_in, const int* in_sizes, int n_in,
                              void* d_out, int out_size, void* d_ws, size_t ws_size,
                              hipStream_t stream) {
    const float* fm1 = (const float*)d_in[0];
    const float* fm2 = (const float*)d_in[1];
    float* out = (float*)d_out;
    wrsl_kernel<<<2048 / NB, 1024, 0, stream>>>(fm1, fm2, out);
}

// Round 7
// 269.913 us; speedup vs baseline: 5.0742x; 1.1465x over previous
//
#include <hip/hip_runtime.h>
#include <hip/hip_fp16.h>
#include <math.h>

#define NTH 5
#define GLO 66
#define GHI 66
#define PS (GLO + 4096 + GHI)   // plane stride in 16B granules = 4228

// theta = {2,1,0,-1,-2} deg; t = -theta*pi/180; alpha=cos t, beta=sin t
#define ALP0 0.99939082701909576f
#define ALP1 0.99984769515639127f
#define ALP2 1.0f
constexpr float ALPc[5] = {ALP0, ALP1, ALP2, ALP1, ALP0};
constexpr float BETc[5] = {0.03489949670250097f, 0.01745240643728351f, 0.0f,
                           -0.01745240643728351f, -0.03489949670250097f};

__device__ __forceinline__ unsigned h2bits(float a, float b) {
    __half2 h = __floats2half2_rn(a, b);
    return *(unsigned*)&h;
}
__device__ __forceinline__ __half2 h2(unsigned u) { return *(__half2*)&u; }

// sum over 16-lane groups: xor1,xor2 via DPP; xor4,xor8 via ds_swizzle.
// result valid at lanes with (lane&15)==0
__device__ __forceinline__ float red16(float x) {
    int t = __builtin_amdgcn_update_dpp(0, __float_as_int(x), 0xB1, 0xF, 0xF, true);
    x += __int_as_float(t);
    t = __builtin_amdgcn_update_dpp(0, __float_as_int(x), 0x4E, 0xF, 0xF, true);
    x += __int_as_float(t);
    t = __builtin_amdgcn_ds_swizzle(__float_as_int(x), 0x101F);  // xor 4
    x += __int_as_float(t);
    t = __builtin_amdgcn_ds_swizzle(__float_as_int(x), 0x201F);  // xor 8
    x += __int_as_float(t);
    return x;
}

// ---- pack fm1/fm2 (f32) -> fp16 layouts in workspace ------------------------
// fm1h: [g=128][px=4096][16 batches]  (32 B granule per pixel)
// fm2h: [g=128][plane=2][px=4096][8 batches] (16 B granule per pixel-plane)
__global__ void pack_kernel(const float* __restrict__ fm1,
                            const float* __restrict__ fm2,
                            __half* __restrict__ fm1h,
                            __half* __restrict__ fm2h) {
    const int g = blockIdx.x;
    const int tid = threadIdx.x;
    const size_t inb = (size_t)g * 16 * 4096;
    for (int p = tid; p < 4096; p += 1024) {
        uint4 wa, wb, va, vb;
        wa.x = h2bits(fm1[inb + 0 * 4096 + p], fm1[inb + 1 * 4096 + p]);
        wa.y = h2bits(fm1[inb + 2 * 4096 + p], fm1[inb + 3 * 4096 + p]);
        wa.z = h2bits(fm1[inb + 4 * 4096 + p], fm1[inb + 5 * 4096 + p]);
        wa.w = h2bits(fm1[inb + 6 * 4096 + p], fm1[inb + 7 * 4096 + p]);
        wb.x = h2bits(fm1[inb + 8 * 4096 + p], fm1[inb + 9 * 4096 + p]);
        wb.y = h2bits(fm1[inb + 10 * 4096 + p], fm1[inb + 11 * 4096 + p]);
        wb.z = h2bits(fm1[inb + 12 * 4096 + p], fm1[inb + 13 * 4096 + p]);
        wb.w = h2bits(fm1[inb + 14 * 4096 + p], fm1[inb + 15 * 4096 + p]);
        va.x = h2bits(fm2[inb + 0 * 4096 + p], fm2[inb + 1 * 4096 + p]);
        va.y = h2bits(fm2[inb + 2 * 4096 + p], fm2[inb + 3 * 4096 + p]);
        va.z = h2bits(fm2[inb + 4 * 4096 + p], fm2[inb + 5 * 4096 + p]);
        va.w = h2bits(fm2[inb + 6 * 4096 + p], fm2[inb + 7 * 4096 + p]);
        vb.x = h2bits(fm2[inb + 8 * 4096 + p], fm2[inb + 9 * 4096 + p]);
        vb.y = h2bits(fm2[inb + 10 * 4096 + p], fm2[inb + 11 * 4096 + p]);
        vb.z = h2bits(fm2[inb + 12 * 4096 + p], fm2[inb + 13 * 4096 + p]);
        vb.w = h2bits(fm2[inb + 14 * 4096 + p], fm2[inb + 15 * 4096 + p]);
        uint4* d1 = (uint4*)(fm1h + ((size_t)g * 4096 + p) * 16);
        d1[0] = wa;
        d1[1] = wb;
        *(uint4*)(fm2h + ((size_t)(g * 2 + 0) * 4096 + p) * 8) = va;
        *(uint4*)(fm2h + ((size_t)(g * 2 + 1) * 4096 + p) * 8) = vb;
    }
}

// ---- denominators: denom[s*5+ti] = sum_px mk (batch-independent) ------------
__global__ void denom_kernel(float* __restrict__ denom) {
    const int bid = blockIdx.x;  // 125
    const int s = bid / 5, ti = bid % 5;
    const int lane = threadIdx.x;  // 64
    const int bh = (s / 5) - 2;
    const int bv = (s % 5) - 2;
    const int ow = 64 - (bh >= 0 ? bh : -bh);
    const int oh = 64 - (bv >= 0 ? bv : -bv);
    const float cx = 0.5f * (float)ow;
    const float cy = 0.5f * (float)oh;
    const float alpha = ALPc[ti], beta = BETc[ti];
    float acc = 0.0f;
    if (lane < ow) {
        const float xs = (float)lane;
        const float hx = fmaf(alpha, xs, (1.0f - alpha) * cx - beta * cy);
        const float hy = fmaf(-beta, xs, beta * cx + (1.0f - alpha) * cy);
        for (int y = 0; y < oh; y++) {
            const float yf = (float)y;
            const float xsrc = fmaf(beta, yf, hx);
            const float ysrc = fmaf(alpha, yf, hy);
            const float x0f = floorf(xsrc), y0f = floorf(ysrc);
            const float wx = xsrc - x0f, wy = ysrc - y0f;
            const int x0 = (int)x0f, y0 = (int)y0f;
            const float ax0 = ((unsigned)x0 < (unsigned)ow) ? (1.f - wx) : 0.f;
            const float ax1 = ((unsigned)(x0 + 1) < (unsigned)ow) ? wx : 0.f;
            const float ay0 = ((unsigned)y0 < (unsigned)oh) ? (1.f - wy) : 0.f;
            const float ay1 = ((unsigned)(y0 + 1) < (unsigned)oh) ? wy : 0.f;
            acc += (ax0 + ax1) * (ay0 + ay1);
        }
    }
    #pragma unroll
    for (int off = 32; off; off >>= 1) acc += __shfl_xor(acc, off);
    if (lane == 0) denom[bid] = acc;
}

// ---- main: 256 blocks = (group g of 16 batches) x (half of 25 shifts) -------
__launch_bounds__(1024, 1)
__global__ void wrsl_main(const __half* __restrict__ fm1h,
                          const __half* __restrict__ fm2h,
                          const float* __restrict__ denom,
                          float* __restrict__ out) {
    __shared__ uint4 lds[2 * PS];        // 135,296 B: 2 planes of img2 + guards
    __shared__ float redm[16][4][80];    // 20,480 B
    __shared__ float colsum[80];

    const int tid = threadIdx.x;
    const int g = blockIdx.x >> 1;
    const int hf = blockIdx.x & 1;
    const int sBeg = hf ? 13 : 0;
    const int sEnd = hf ? 25 : 13;

    // stage fm2h group slice (two planes), zero guards
    {
        const uint4* src = (const uint4*)(fm2h + (size_t)g * 2 * 4096 * 8);
        for (int i = tid; i < 4096; i += 1024) {
            lds[GLO + i] = src[i];
            lds[PS + GLO + i] = src[4096 + i];
        }
        if (tid < 2 * (GLO + GHI)) {
            const int pl = (tid >= GLO + GHI) ? 1 : 0;
            const int j = tid - pl * (GLO + GHI);
            const int off = (j < GLO) ? j : (GLO + 4096 + (j - GLO));
            lds[pl * PS + off] = make_uint4(0u, 0u, 0u, 0u);
        }
    }
    const int lane = tid & 63, wid = tid >> 6;
    const float xs = (float)lane;
    __syncthreads();

    float best = 3.4028234663852886e38f;  // meaningful on tid<16

    for (int s = sBeg; s < sEnd; s++) {
        const int bh = (s / 5) - 2;
        const int bv = (s % 5) - 2;
        const int ox1 = bh >= 0 ? 0 : -bh;
        const int ox2 = bh >= 0 ? bh : 0;
        const int ow = 64 - (bh >= 0 ? bh : -bh);
        const int oy1 = bv >= 0 ? 0 : -bv;
        const int oy2 = bv >= 0 ? bv : 0;
        const int oh = 64 - (bv >= 0 ? bv : -bv);
        const float cx = 0.5f * (float)ow;
        const float cy = 0.5f * (float)oh;
        const float xinf = (lane < ow) ? 1.0f : 0.0f;
        const __half2 xmp = __float2half2_rn(xinf);
        const int xcap = ox1 + min(lane, ow - 1);

        // r1 (16 batches) for this wave's 4 rows -> 32 VGPRs, reused over 5 thetas
        uint4 rA[4], rB[4];
        #pragma unroll
        for (int k = 0; k < 4; k++) {
            const int p1 = (oy1 + min(wid + 16 * k, oh - 1)) * 64 + xcap;
            const uint4* rp = (const uint4*)(fm1h + ((size_t)g * 4096 + p1) * 16);
            rA[k] = rp[0];
            rB[k] = rp[1];
        }

        #pragma unroll
        for (int ti = 0; ti < NTH; ti++) {
            const __half2 z2 = __float2half2_rn(0.0f);
            __half2 seA[4] = {z2, z2, z2, z2};
            __half2 seB[4] = {z2, z2, z2, z2};
            if (ti == 2) {
                // identity rotation: xsrc=x, ysrc=y exactly; mk=1 in-window
                #pragma unroll
                for (int k = 0; k < 4; k++) {
                    const int y = wid + 16 * k;
                    if (y < oh) {
                        const int idx = GLO + (oy2 + y) * 64 + ox2 + lane;
                        const uint4 qa = lds[idx];
                        const uint4 qb = lds[PS + idx];
                        #define LIGHT(SE, R, Q, C)                                     \
                        {                                                              \
                            __half2 d = __hmul2(__hsub2(h2(R[k].C), h2(Q.C)), xmp);    \
                            SE = __hfma2(d, d, SE);                                    \
                        }
                        LIGHT(seA[0], rA, qa, x) LIGHT(seA[1], rA, qa, y)
                        LIGHT(seA[2], rA, qa, z) LIGHT(seA[3], rA, qa, w)
                        LIGHT(seB[0], rB, qb, x) LIGHT(seB[1], rB, qb, y)
                        LIGHT(seB[2], rB, qb, z) LIGHT(seB[3], rB, qb, w)
                        #undef LIGHT
                    }
                }
            } else {
                const float alpha = ALPc[ti], beta = BETc[ti];
                const float hx = fmaf(alpha, xs, (1.0f - alpha) * cx - beta * cy);
                const float hy = fmaf(-beta, xs, beta * cx + (1.0f - alpha) * cy);
                #pragma unroll
                for (int k = 0; k < 4; k++) {
                    const int y = wid + 16 * k;
                    if (y < oh) {
                        const float yf = (float)y;
                        const float xsrc = fmaf(beta, yf, hx);
                        const float ysrc = fmaf(alpha, yf, hy);
                        const float x0f = floorf(xsrc), y0f = floorf(ysrc);
                        const float wx = xsrc - x0f, wy = ysrc - y0f;
                        const int x0 = (int)x0f, y0 = (int)y0f;
                        const float ax0 = ((unsigned)x0 < (unsigned)ow) ? (1.f - wx) : 0.f;
                        const float ax1 = ((unsigned)(x0 + 1) < (unsigned)ow) ? wx : 0.f;
                        const float ay0 = ((unsigned)y0 < (unsigned)oh) ? (1.f - wy) : 0.f;
                        const float ay1 = ((unsigned)(y0 + 1) < (unsigned)oh) ? wy : 0.f;
                        const int x0c = min(max(x0, -1), ow - 1);  // addressing only
                        const int y0c = min(max(y0, -1), oh - 1);
                        const float mk = (ax0 + ax1) * (ay0 + ay1) * xinf;
                        const __half2 w00p = __float2half2_rn(ay0 * ax0);
                        const __half2 w01p = __float2half2_rn(ay0 * ax1);
                        const __half2 w10p = __float2half2_rn(ay1 * ax0);
                        const __half2 w11p = __float2half2_rn(ay1 * ax1);
                        const __half2 mkp = __float2half2_rn(mk);
                        const int b0 = GLO + (y0c + oy2) * 64 + (x0c + ox2);
                        {
                            const uint4 q00 = lds[b0], q01 = lds[b0 + 1];
                            const uint4 q10 = lds[b0 + 64], q11 = lds[b0 + 65];
                            #define FULL(SE, R, C)                                     \
                            {                                                          \
                                __half2 r = __hmul2(w00p, h2(q00.C));                  \
                                r = __hfma2(w01p, h2(q01.C), r);                       \
                                r = __hfma2(w10p, h2(q10.C), r);                       \
                                r = __hfma2(w11p, h2(q11.C), r);                       \
                                __half2 d = __hsub2(h2(R[k].C), r);                    \
                                SE = __hfma2(__hmul2(d, d), mkp, SE);                  \
                            }
                            FULL(seA[0], rA, x) FULL(seA[1], rA, y)
                            FULL(seA[2], rA, z) FULL(seA[3], rA, w)
                            #undef FULL
                        }
                        {
                            const uint4 q00 = lds[PS + b0], q01 = lds[PS + b0 + 1];
                            const uint4 q10 = lds[PS + b0 + 64], q11 = lds[PS + b0 + 65];
                            #define FULL(SE, R, C)                                     \
                            {                                                          \
                                __half2 r = __hmul2(w00p, h2(q00.C));                  \
                                r = __hfma2(w01p, h2(q01.C), r);                       \
                                r = __hfma2(w10p, h2(q10.C), r);                       \
                                r = __hfma2(w11p, h2(q11.C), r);                       \
                                __half2 d = __hsub2(h2(R[k].C), r);                    \
                                SE = __hfma2(__hmul2(d, d), mkp, SE);                  \
                            }
                            FULL(seB[0], rB, x) FULL(seB[1], rB, y)
                            FULL(seB[2], rB, z) FULL(seB[3], rB, w)
                            #undef FULL
                        }
                    }
                }
            }
            // unpack to f32, reduce over 16-lane groups, leaders write partials
            float as[16];
            #pragma unroll
            for (int j = 0; j < 4; j++) {
                float2 fa = __half22float2(seA[j]);
                float2 fb = __half22float2(seB[j]);
                as[2 * j] = fa.x;
                as[2 * j + 1] = fa.y;
                as[8 + 2 * j] = fb.x;
                as[8 + 2 * j + 1] = fb.y;
            }
            #pragma unroll
            for (int v = 0; v < 16; v++) as[v] = red16(as[v]);
            if ((lane & 15) == 0) {
                float* dst = &redm[wid][lane >> 4][ti * 16];
                #pragma unroll
                for (int v = 0; v < 16; v++) dst[v] = as[v];
            }
        }
        __syncthreads();  // B1: redm complete
        if (tid < 80) {
            float sum = 0.0f;
            #pragma unroll 8
            for (int w = 0; w < 16; w++) {
                sum += redm[w][0][tid] + redm[w][1][tid] + redm[w][2][tid] + redm[w][3][tid];
            }
            colsum[tid] = sum;
        }
        __syncthreads();  // B2: colsum ready, redm reusable
        if (tid < 16) {
            #pragma unroll
            for (int t2 = 0; t2 < NTH; t2++)
                best = fminf(best, colsum[t2 * 16 + tid] / denom[s * 5 + t2]);
        }
    }
    if (tid < 16)
        atomicMin((unsigned int*)&out[g * 16 + tid], __float_as_uint(best));
}

extern "C" void kernel_launch(void* const* d_in, const int* in_sizes, int n_in,
                              void* d_out, int out_size, void* d_ws, size_t ws_size,
                              hipStream_t stream) {
    const float* fm1 = (const float*)d_in[0];
    const float* fm2 = (const float*)d_in[1];
    float* out = (float*)d_out;
    // workspace layout: fm1h 16 MB | fm2h 16 MB | denom 500 B  (needs ws >= 32 MB + 512 B)
    __half* fm1h = (__half*)d_ws;
    __half* fm2h = (__half*)((char*)d_ws + (16u << 20));
    float* denom = (float*)((char*)d_ws + (32u << 20));

    // init output to +huge (positive-float bit pattern) for atomicMin; replay-safe
    hipMemsetAsync(d_out, 0x7F, (size_t)out_size * 4, stream);
    pack_kernel<<<128, 1024, 0, stream>>>(fm1, fm2, fm1h, fm2h);
    denom_kernel<<<125, 64, 0, stream>>>(denom);
    wrsl_main<<<256, 1024, 0, stream>>>(fm1h, fm2h, denom, out);
}